// Round 8
// baseline (88.923 us; speedup 1.0000x reference)
//
#include <hip/hip_runtime.h>

// MultiLinear: out[n,h] = sum_d x[n,d] * W[idx[n],d,h] + b[idx[n],h]
// N=2048, D=512, H=512, NH=16. fp32 in/out, bf16 MFMA internally.
//
// R8: single dispatch. R7's null result (-0.4us from major staging/pipeline
// fixes) + corrected arithmetic (W stripe = 64KB/block, not 256KB) says the
// kernels were already ~5-6us and total is dominated by the harness floor
// (256MiB ws-poison ~43.5us + restores + graph-node gaps ~81us). Remaining
// lever: drop the xconv dispatch (node gap + serialization + xb round-trip)
// by loading x fp32 directly and packing bf16 via v_perm truncation, in two
// 16-float4 half-batches per m-tile (~64 VGPRs in flight, no R4 spill trap).

#define N_SAMPLES 2048
#define DIM       512
#define HDIM      512
#define N_HEADS   16
#define SH        32              // h-columns per block = 2 MFMA n-tiles
#define BPITCH    520             // ushorts per Bl row: 1040B, 16B-aligned rows;
                                  // b128 compute reads at conflict-free baseline

typedef __attribute__((ext_vector_type(8))) short bf16x8;
typedef __attribute__((ext_vector_type(4))) float floatx4;

__device__ inline unsigned short f2bf_rne(float f) {
    union { float f; unsigned u; } v; v.f = f;
    return (unsigned short)((v.u + 0x7FFFu + ((v.u >> 16) & 1u)) >> 16);
}
__device__ inline unsigned bfpack_rne(float lo, float hi) {   // bf16(lo)|bf16(hi)<<16
    return (unsigned)f2bf_rne(lo) | ((unsigned)f2bf_rne(hi) << 16);
}
// two fp32 -> packed bf16x2 by truncation: one v_perm_b32
__device__ inline unsigned bf2_trunc(float lo, float hi) {
    return __builtin_amdgcn_perm(__float_as_uint(hi), __float_as_uint(lo), 0x07060302u);
}
__device__ inline bf16x8 pack_a(const float4 u0, const float4 u1) {
    union { bf16x8 v; unsigned u[4]; } r;
    r.u[0] = bf2_trunc(u0.x, u0.y);
    r.u[1] = bf2_trunc(u0.z, u0.w);
    r.u[2] = bf2_trunc(u1.x, u1.y);
    r.u[3] = bf2_trunc(u1.z, u1.w);
    return r.v;
}

__global__ __launch_bounds__(256, 2) void fused(
    const float* __restrict__ x,      // N x D fp32
    const int*   __restrict__ idx,    // N
    const float* __restrict__ w,      // NH x D x H fp32
    const float* __restrict__ bias,   // NH x H fp32
    float*       __restrict__ out)    // N x H fp32
{
    __shared__ unsigned short Bl[SH * BPITCH];      // 33.3 KB, [h][d] bf16
    __shared__ unsigned short slist[N_SAMPLES];     // 4 KB
    __shared__ int wcnt[4];

    const int bid  = blockIdx.x;                    // 256 blocks = head x 16 stripes
    const int head = bid >> 4;
    const int h0   = (bid & 15) * SH;
    const int t    = threadIdx.x;
    const int wave = t >> 6;
    const int lane = t & 63;
    const int l16  = lane & 15;
    const int quad = lane >> 4;

    // ---- idx loads first (oldest in flight; ballot waits only on these) ----
    int myidx[8];
    #pragma unroll
    for (int c = 0; c < 8; ++c)
        myidx[c] = idx[(wave * 8 + c) * 64 + lane];

    // ---- issue ALL W loads into regs (row-contiguous: lanes 0..7 cover one
    //      128B d-row segment; 16 float4/thread = whole 512d x 32h stripe) ----
    const int hh = (t & 7) * 4;                     // 0..28
    const int dg = t >> 3;                          // 0..31, d-range [dg*16, +16)
    const float* wg = w + (size_t)head * DIM * HDIM + h0;
    float4 q[16];
    #pragma unroll
    for (int s = 0; s < 16; ++s)
        q[s] = *(const float4*)(wg + (size_t)(dg * 16 + s) * HDIM + hh);

    // ---- ballot compaction (overlaps W-load flight; waits only idx) ----
    unsigned long long masks[8];
    {
        int mycnt = 0;
        #pragma unroll
        for (int c = 0; c < 8; ++c) {
            masks[c] = __ballot(myidx[c] == head);
            mycnt += __popcll(masks[c]);
        }
        if (lane == 0) wcnt[wave] = mycnt;
    }
    __syncthreads();                                // wcnt visible
    int cnt = 0, base = 0;
    #pragma unroll
    for (int i = 0; i < 4; ++i) { if (i < wave) base += wcnt[i]; cnt += wcnt[i]; }
    {
        int pos = base;
        #pragma unroll
        for (int c = 0; c < 8; ++c) {
            const unsigned long long m = masks[c];
            if (m & (1ull << lane)) {
                const int rank = __popcll(m & ((1ull << lane) - 1ull));
                slist[pos + rank] = (unsigned short)((wave * 8 + c) * 64 + lane);
            }
            pos += __popcll(m);
        }
    }

    // ---- convert staged W and write Bl[h][d] (packed d-pairs, b32 writes) ----
    #pragma unroll
    for (int p = 0; p < 8; ++p) {
        const int d = dg * 16 + 2 * p;
        const float4 qa = q[2 * p], qb = q[2 * p + 1];
        *(unsigned*)&Bl[(hh + 0) * BPITCH + d] = bfpack_rne(qa.x, qb.x);
        *(unsigned*)&Bl[(hh + 1) * BPITCH + d] = bfpack_rne(qa.y, qb.y);
        *(unsigned*)&Bl[(hh + 2) * BPITCH + d] = bfpack_rne(qa.z, qb.z);
        *(unsigned*)&Bl[(hh + 3) * BPITCH + d] = bfpack_rne(qa.w, qb.w);
    }
    __syncthreads();                                // Bl + slist visible

    const int   mt  = (cnt + 15) >> 4;              // m-tiles for this head
    const float bv0 = bias[head * HDIM + h0 + l16];
    const float bv1 = bias[head * HDIM + h0 + 16 + l16];

    // ---- m-loop: wave owns m-tiles j = wave, wave+4, ...; A from fp32 x in
    //      two 16-float4 half-batches (64 VGPRs in flight), packed via v_perm ----
    for (int j = wave; j < mt; j += 4) {
        const int mg  = j * 16 + l16;
        const int row = slist[mg < cnt ? mg : cnt - 1];
        const float* xp = x + (size_t)row * DIM + quad * 8;

        bf16x8 a[16];
        {
            float4 u[16];
            #pragma unroll
            for (int ks = 0; ks < 8; ++ks) {        // half-batch 0: d < 256
                u[2 * ks]     = *(const float4*)(xp + ks * 32);
                u[2 * ks + 1] = *(const float4*)(xp + ks * 32 + 4);
            }
            #pragma unroll
            for (int ks = 0; ks < 8; ++ks)
                a[ks] = pack_a(u[2 * ks], u[2 * ks + 1]);
            #pragma unroll
            for (int ks = 8; ks < 16; ++ks) {       // half-batch 1: d >= 256
                u[2 * (ks - 8)]     = *(const float4*)(xp + ks * 32);
                u[2 * (ks - 8) + 1] = *(const float4*)(xp + ks * 32 + 4);
            }
            #pragma unroll
            for (int ks = 8; ks < 16; ++ks)
                a[ks] = pack_a(u[2 * (ks - 8)], u[2 * (ks - 8) + 1]);
        }

        floatx4 acc0 = {0.f, 0.f, 0.f, 0.f};
        floatx4 acc1 = {0.f, 0.f, 0.f, 0.f};
        #pragma unroll
        for (int ks = 0; ks < 16; ++ks) {
            const bf16x8 b0 = *(const bf16x8*)&Bl[l16 * BPITCH + ks * 32 + quad * 8];
            const bf16x8 b1 = *(const bf16x8*)&Bl[(16 + l16) * BPITCH + ks * 32 + quad * 8];
            acc0 = __builtin_amdgcn_mfma_f32_16x16x32_bf16(a[ks], b0, acc0, 0, 0, 0);
            acc1 = __builtin_amdgcn_mfma_f32_16x16x32_bf16(a[ks], b1, acc1, 0, 0, 0);
        }

        // C[m][n]: n = l16 (h), sample row = quad*4 + r; 64B-contiguous stores
        #pragma unroll
        for (int r = 0; r < 4; ++r) {
            const int mm = j * 16 + quad * 4 + r;
            if (mm < cnt) {
                const int rg = slist[mm];
                out[(size_t)rg * HDIM + h0 + l16]      = acc0[r] + bv0;
                out[(size_t)rg * HDIM + h0 + 16 + l16] = acc1[r] + bv1;
            }
        }
    }
}

extern "C" void kernel_launch(void* const* d_in, const int* in_sizes, int n_in,
                              void* d_out, int out_size, void* d_ws, size_t ws_size,
                              hipStream_t stream) {
    const float* x   = (const float*)d_in[0];
    const int*   idx = (const int*)  d_in[1];
    const float* w   = (const float*)d_in[2];
    const float* b   = (const float*)d_in[3];
    float*       out = (float*)d_out;

    fused<<<N_HEADS * (HDIM / SH), 256, 0, stream>>>(x, idx, w, b, out);
}

// Round 9
// 87.966 us; speedup vs baseline: 1.0109x; 1.0109x over previous
//
#include <hip/hip_runtime.h>

// MultiLinear: out[n,h] = sum_d x[n,d] * W[idx[n],d,h] + b[idx[n],h]
// N=2048, D=512, H=512, NH=16. fp32 in/out, bf16 MFMA internally.
//
// R9: revert to R7 (best measured, 87.3us) for confirmation. Session finding:
// totals are dominated by a ~82us harness floor (256MiB ws 0xAA poison
// ~43.5us at 77% HBM peak + d_in restore copies + graph-node gaps); three
// structurally different kernels (R6/R7/R8) land within 1.6us of each other.
// R7's split (tiny xconv + bf16-fed fused) has the cheapest critical path:
// 1 x 16B bf16 load per A-frag vs R8's 2 x fp32 loads + 4 v_perm.
//
// Kernel design (what made the controllable part ~5us, from 75us in R1):
//  - head-clustered tiles via in-block ballot compaction (no atomics)
//  - per-block-unique W stripe (512d x 32h, 64KB) staged fp32->bf16 LDS once;
//    W read exactly once chip-wide
//  - mfma_f32_16x16x32_bf16, one A-load set feeds two n-tile chains
//  - row-contiguous staging loads (16 cache lines/inst), b32 packed LDS writes
//  - x pre-converted to bf16 (halves A bytes, 1 load-inst/frag)

#define N_SAMPLES 2048
#define DIM       512
#define HDIM      512
#define N_HEADS   16
#define SH        32              // h-columns per block = 2 MFMA n-tiles
#define BPITCH    520             // ushorts per Bl row: 1040B, 16B-aligned rows;
                                  // b128 compute reads at conflict-free baseline

typedef __attribute__((ext_vector_type(8))) short bf16x8;
typedef __attribute__((ext_vector_type(4))) float floatx4;

__device__ inline unsigned short f2bf_rne(float f) {
    union { float f; unsigned u; } v; v.f = f;
    return (unsigned short)((v.u + 0x7FFFu + ((v.u >> 16) & 1u)) >> 16);
}
__device__ inline unsigned bfpack_rne(float lo, float hi) {   // bf16(lo)|bf16(hi)<<16
    return (unsigned)f2bf_rne(lo) | ((unsigned)f2bf_rne(hi) << 16);
}

// ---- prep: x (fp32) -> xb (bf16 RNE), 8 elems/thread, 16B stores ----
__global__ __launch_bounds__(256) void xconv(const float* __restrict__ x,
                                             unsigned* __restrict__ xb) {
    const int i = blockIdx.x * 256 + threadIdx.x;      // 0..131071
    const float4 v0 = *(const float4*)(x + i * 8);
    const float4 v1 = *(const float4*)(x + i * 8 + 4);
    uint4 o;
    o.x = bfpack_rne(v0.x, v0.y);
    o.y = bfpack_rne(v0.z, v0.w);
    o.z = bfpack_rne(v1.x, v1.y);
    o.w = bfpack_rne(v1.z, v1.w);
    *(uint4*)(xb + i * 4) = o;
}

__global__ __launch_bounds__(256, 2) void fused(
    const unsigned short* __restrict__ xb,   // N x D bf16
    const int*   __restrict__ idx,           // N
    const float* __restrict__ w,             // NH x D x H fp32
    const float* __restrict__ bias,          // NH x H fp32
    float*       __restrict__ out)           // N x H fp32
{
    __shared__ unsigned short Bl[SH * BPITCH];      // 33.3 KB, [h][d] bf16
    __shared__ unsigned short slist[N_SAMPLES];     // 4 KB
    __shared__ int wcnt[4];

    const int bid  = blockIdx.x;                    // 256 blocks = head x 16 stripes
    const int head = bid >> 4;
    const int h0   = (bid & 15) * SH;
    const int t    = threadIdx.x;
    const int wave = t >> 6;
    const int lane = t & 63;
    const int l16  = lane & 15;
    const int quad = lane >> 4;

    // ---- idx loads first (oldest in flight; ballot waits only on these) ----
    int myidx[8];
    #pragma unroll
    for (int c = 0; c < 8; ++c)
        myidx[c] = idx[(wave * 8 + c) * 64 + lane];

    // ---- issue ALL W loads into regs (row-contiguous: lanes 0..7 cover one
    //      128B d-row segment; 16 float4/thread = whole 512d x 32h stripe) ----
    const int hh = (t & 7) * 4;                     // 0..28
    const int dg = t >> 3;                          // 0..31, d-range [dg*16, +16)
    const float* wg = w + (size_t)head * DIM * HDIM + h0;
    float4 q[16];
    #pragma unroll
    for (int s = 0; s < 16; ++s)
        q[s] = *(const float4*)(wg + (size_t)(dg * 16 + s) * HDIM + hh);

    // ---- ballot compaction (overlaps W-load flight; waits only idx) ----
    unsigned long long masks[8];
    {
        int mycnt = 0;
        #pragma unroll
        for (int c = 0; c < 8; ++c) {
            masks[c] = __ballot(myidx[c] == head);
            mycnt += __popcll(masks[c]);
        }
        if (lane == 0) wcnt[wave] = mycnt;
    }
    __syncthreads();                                // wcnt visible
    int cnt = 0, base = 0;
    #pragma unroll
    for (int i = 0; i < 4; ++i) { if (i < wave) base += wcnt[i]; cnt += wcnt[i]; }
    {
        int pos = base;
        #pragma unroll
        for (int c = 0; c < 8; ++c) {
            const unsigned long long m = masks[c];
            if (m & (1ull << lane)) {
                const int rank = __popcll(m & ((1ull << lane) - 1ull));
                slist[pos + rank] = (unsigned short)((wave * 8 + c) * 64 + lane);
            }
            pos += __popcll(m);
        }
    }

    // ---- convert staged W and write Bl[h][d] (packed d-pairs, b32 writes) ----
    #pragma unroll
    for (int p = 0; p < 8; ++p) {
        const int d = dg * 16 + 2 * p;
        const float4 qa = q[2 * p], qb = q[2 * p + 1];
        *(unsigned*)&Bl[(hh + 0) * BPITCH + d] = bfpack_rne(qa.x, qb.x);
        *(unsigned*)&Bl[(hh + 1) * BPITCH + d] = bfpack_rne(qa.y, qb.y);
        *(unsigned*)&Bl[(hh + 2) * BPITCH + d] = bfpack_rne(qa.z, qb.z);
        *(unsigned*)&Bl[(hh + 3) * BPITCH + d] = bfpack_rne(qa.w, qb.w);
    }
    __syncthreads();                                // Bl + slist visible

    const int   mt  = (cnt + 15) >> 4;              // m-tiles for this head
    const float bv0 = bias[head * HDIM + h0 + l16];
    const float bv1 = bias[head * HDIM + h0 + 16 + l16];

    // ---- software-pipelined m-loop: wave owns m-tiles j = wave, wave+4, ... ----
    int j = wave;
    bf16x8 a[16];
    if (j < mt) {
        const int mg  = j * 16 + l16;
        const int row = slist[mg < cnt ? mg : cnt - 1];
        const unsigned short* ap = xb + (size_t)row * DIM + quad * 8;
        #pragma unroll
        for (int ks = 0; ks < 16; ++ks) a[ks] = *(const bf16x8*)(ap + ks * 32);
    }
    for (; j < mt; j += 4) {
        bf16x8 an[16];
        const int jn = j + 4;
        if (jn < mt) {                              // prefetch next tile's A
            const int mg  = jn * 16 + l16;
            const int row = slist[mg < cnt ? mg : cnt - 1];
            const unsigned short* ap = xb + (size_t)row * DIM + quad * 8;
            #pragma unroll
            for (int ks = 0; ks < 16; ++ks) an[ks] = *(const bf16x8*)(ap + ks * 32);
        }

        floatx4 acc0 = {0.f, 0.f, 0.f, 0.f};
        floatx4 acc1 = {0.f, 0.f, 0.f, 0.f};
        #pragma unroll
        for (int ks = 0; ks < 16; ++ks) {
            const bf16x8 b0 = *(const bf16x8*)&Bl[l16 * BPITCH + ks * 32 + quad * 8];
            const bf16x8 b1 = *(const bf16x8*)&Bl[(16 + l16) * BPITCH + ks * 32 + quad * 8];
            acc0 = __builtin_amdgcn_mfma_f32_16x16x32_bf16(a[ks], b0, acc0, 0, 0, 0);
            acc1 = __builtin_amdgcn_mfma_f32_16x16x32_bf16(a[ks], b1, acc1, 0, 0, 0);
        }

        // C[m][n]: n = l16 (h), sample row = quad*4 + r; 64B-contiguous stores
        #pragma unroll
        for (int r = 0; r < 4; ++r) {
            const int mm = j * 16 + quad * 4 + r;
            if (mm < cnt) {
                const int rg = slist[mm];
                out[(size_t)rg * HDIM + h0 + l16]      = acc0[r] + bv0;
                out[(size_t)rg * HDIM + h0 + 16 + l16] = acc1[r] + bv1;
            }
        }

        #pragma unroll
        for (int ks = 0; ks < 16; ++ks) a[ks] = an[ks];
    }
}

extern "C" void kernel_launch(void* const* d_in, const int* in_sizes, int n_in,
                              void* d_out, int out_size, void* d_ws, size_t ws_size,
                              hipStream_t stream) {
    const float* x   = (const float*)d_in[0];
    const int*   idx = (const int*)  d_in[1];
    const float* w   = (const float*)d_in[2];
    const float* b   = (const float*)d_in[3];
    float*       out = (float*)d_out;

    unsigned* xb = (unsigned*)d_ws;                 // 2 MB bf16 x

    xconv<<<512, 256, 0, stream>>>(x, xb);
    fused<<<N_HEADS * (HDIM / SH), 256, 0, stream>>>((const unsigned short*)xb, idx, w, b, out);
}